// Round 1
// baseline (607.333 us; speedup 1.0000x reference)
//
#include <hip/hip_runtime.h>
#include <hip/hip_bf16.h>
#include <hip/hip_fp16.h>
#include <math.h>

#define D_IN   128
#define D_RNI  32
#define HID    256

typedef _Float16 half8 __attribute__((ext_vector_type(8)));
typedef float    f32x4 __attribute__((ext_vector_type(4)));

// ---------------------------------------------------------------------------
// Edge dtype detection: int64 edges (values < 2^31) have all odd words zero.
// ---------------------------------------------------------------------------
__global__ void k_detect(const unsigned int* __restrict__ w, int nwords, int* __restrict__ mode) {
    __shared__ unsigned int red[256];
    unsigned int acc = 0;
    for (int i = threadIdx.x; i < 1024; i += 256) {
        int idx = 2 * i + 1;
        if (idx < nwords) acc |= w[idx];
    }
    red[threadIdx.x] = acc;
    __syncthreads();
    for (int s = 128; s > 0; s >>= 1) {
        if (threadIdx.x < s) red[threadIdx.x] |= red[threadIdx.x + s];
        __syncthreads();
    }
    if (threadIdx.x == 0) *mode = (red[0] == 0u) ? 1 : 0;
}

__global__ void k_count(const unsigned int* __restrict__ ew, const int* __restrict__ mode_p,
                        int* __restrict__ counts, int e) {
    int mode = *mode_p;
    int i = blockIdx.x * 256 + threadIdx.x;
    if (i >= e) return;
    int d = mode ? (int)ew[2 * ((size_t)e + i)] : (int)ew[(size_t)e + i];
    atomicAdd(&counts[d], 1);
}

// ---------------------------------------------------------------------------
// Hierarchical scan
// ---------------------------------------------------------------------------
__global__ __launch_bounds__(1024) void k_scan1(const int* __restrict__ counts,
                                                int* __restrict__ incl,
                                                int* __restrict__ bsum, int n) {
    __shared__ int sd[1024];
    int t = threadIdx.x;
    int i = blockIdx.x * 1024 + t;
    int v = (i < n) ? counts[i] : 0;
    sd[t] = v;
    __syncthreads();
    for (int off = 1; off < 1024; off <<= 1) {
        int tmp = (t >= off) ? sd[t - off] : 0;
        __syncthreads();
        sd[t] += tmp;
        __syncthreads();
    }
    if (i < n) incl[i] = sd[t];
    if (t == 1023) bsum[blockIdx.x] = sd[1023];
}

__global__ __launch_bounds__(1024) void k_scan2(int* __restrict__ bsum, int nb) {
    __shared__ int sd[1024];
    int t = threadIdx.x;
    int v = (t < nb) ? bsum[t] : 0;
    sd[t] = v;
    __syncthreads();
    for (int off = 1; off < 1024; off <<= 1) {
        int tmp = (t >= off) ? sd[t - off] : 0;
        __syncthreads();
        sd[t] += tmp;
        __syncthreads();
    }
    if (t < nb) bsum[t] = sd[t] - v;
    if (t == nb - 1) bsum[nb] = sd[t];
}

__global__ void k_scan3(const int* __restrict__ counts, const int* __restrict__ incl,
                        const int* __restrict__ bsum,
                        int* __restrict__ rowptr, int* __restrict__ cursor,
                        float* __restrict__ dis, int n, int nb) {
    int i = blockIdx.x * 256 + threadIdx.x;
    if (i >= n) return;
    int excl = incl[i] - counts[i] + bsum[i >> 10];
    rowptr[i] = excl;
    cursor[i] = excl;
    dis[i] = 1.0f / sqrtf((float)(counts[i] + 1));
    if (i == 0) rowptr[n] = bsum[nb];
}

__global__ void k_scatter(const unsigned int* __restrict__ ew, const int* __restrict__ mode_p,
                          int* __restrict__ cursor, int* __restrict__ csr, int e) {
    int mode = *mode_p;
    int i = blockIdx.x * 256 + threadIdx.x;
    if (i >= e) return;
    int s, d;
    if (mode) {
        s = (int)ew[2 * (size_t)i];
        d = (int)ew[2 * ((size_t)e + i)];
    } else {
        s = (int)ew[(size_t)i];
        d = (int)ew[(size_t)e + i];
    }
    int pos = atomicAdd(&cursor[d], 1);
    csr[pos] = s;
}

// W[K][N] fp32 -> Wt[N][K] fp16 (transpose + cast; tiny matrices)
__global__ void k_cvt_wt(const float* __restrict__ W, __half* __restrict__ Wt,
                         int K, int N, int total) {
    int i = blockIdx.x * 256 + threadIdx.x;
    if (i >= total) return;
    int k = i / N, nn = i - k * N;
    Wt[(size_t)nn * K + k] = __float2half(W[i]);
}

// ---------------------------------------------------------------------------
// fp16 MFMA GEMM: C[M x 256] = A[M x K] @ Bt^T  (Bt:[N=256][K] fp16).
// A_F32: A (and optional A2, concat along K at KA) are fp32, converted to fp16
// during LDS staging (fuses the input cast; K-split KA must be KT-aligned).
// Block: 256 threads = 4 waves; tile 64 M x 256 N; wave w owns N [64w, 64w+64).
// v_mfma_f32_16x16x32_f16; LDS rows padded to 40 halves (no 4-way+ conflicts).
// ---------------------------------------------------------------------------
#define KT 32
#define LSTR 40
template <bool A_F32, bool ADD_BIAS, bool HALF_OUT>
__global__ __launch_bounds__(256) void k_mgemm(const void* __restrict__ Av, int strideA, int KA,
                                               const void* __restrict__ A2v, int strideA2,
                                               const __half* __restrict__ Bt,
                                               const float* __restrict__ bias,
                                               void* Cv, int M, int K) {
    __shared__ __half As[64 * LSTR];
    __shared__ __half Bs[256 * LSTR];
    int tid = threadIdx.x;
    int wave = tid >> 6, lane = tid & 63;
    int q = lane >> 4, m16 = lane & 15;
    int r0 = blockIdx.x * 64;

    f32x4 acc[4][4] = {};

    for (int k0 = 0; k0 < K; k0 += KT) {
        __syncthreads();
        // stage A tile: 64 rows x 32 k (8 halves per thread)
        {
            int r = tid >> 2, kq = (tid & 3) * 8;
            int row = r0 + r; if (row >= M) row = M - 1;
            if (A_F32) {
                const float* src; int stride, kk0;
                if (k0 < KA) { src = (const float*)Av;  stride = strideA;  kk0 = k0; }
                else         { src = (const float*)A2v; stride = strideA2; kk0 = k0 - KA; }
                const float* p = &src[(size_t)row * stride + kk0 + kq];
                float4 va = *reinterpret_cast<const float4*>(p);
                float4 vb = *reinterpret_cast<const float4*>(p + 4);
                union { __half2 h2[4]; uint4 u; } uu;
                uu.h2[0] = __floats2half2_rn(va.x, va.y);
                uu.h2[1] = __floats2half2_rn(va.z, va.w);
                uu.h2[2] = __floats2half2_rn(vb.x, vb.y);
                uu.h2[3] = __floats2half2_rn(vb.z, vb.w);
                *reinterpret_cast<uint4*>(&As[r * LSTR + kq]) = uu.u;
            } else {
                const __half* src = (const __half*)Av;
                uint4 v = *reinterpret_cast<const uint4*>(&src[(size_t)row * strideA + k0 + kq]);
                *reinterpret_cast<uint4*>(&As[r * LSTR + kq]) = v;
            }
        }
        // stage B tile: 256 n x 32 k
        {
            int nb = tid >> 2, kq = (tid & 3) * 8;
            #pragma unroll
            for (int i = 0; i < 4; ++i) {
                int nn = nb + i * 64;
                uint4 v = *reinterpret_cast<const uint4*>(&Bt[(size_t)nn * K + k0 + kq]);
                *reinterpret_cast<uint4*>(&Bs[nn * LSTR + kq]) = v;
            }
        }
        __syncthreads();

        half8 af[4], bf[4];
        #pragma unroll
        for (int mi = 0; mi < 4; ++mi)
            af[mi] = *reinterpret_cast<const half8*>(&As[(mi * 16 + m16) * LSTR + q * 8]);
        #pragma unroll
        for (int ni = 0; ni < 4; ++ni)
            bf[ni] = *reinterpret_cast<const half8*>(&Bs[(wave * 64 + ni * 16 + m16) * LSTR + q * 8]);
        #pragma unroll
        for (int mi = 0; mi < 4; ++mi)
            #pragma unroll
            for (int ni = 0; ni < 4; ++ni)
                acc[mi][ni] = __builtin_amdgcn_mfma_f32_16x16x32_f16(af[mi], bf[ni], acc[mi][ni], 0, 0, 0);
    }

    // epilogue
    #pragma unroll
    for (int mi = 0; mi < 4; ++mi) {
        #pragma unroll
        for (int r = 0; r < 4; ++r) {
            int row = r0 + mi * 16 + q * 4 + r;
            if (row >= M) continue;
            #pragma unroll
            for (int ni = 0; ni < 4; ++ni) {
                int col = wave * 64 + ni * 16 + m16;
                float v = acc[mi][ni][r];
                if (ADD_BIAS) v += bias[col];
                if (HALF_OUT) ((__half*)Cv)[(size_t)row * HID + col] = __float2half(v);
                else          ((float*)Cv)[(size_t)row * HID + col] = v;
            }
        }
    }
}

// ---------------------------------------------------------------------------
// Aggregation, channel-split 8 ways, XCD-pinned:
// h[i,c] = relu( sum_e xh[src_e,c]*dis[src]*dis[i] + xh[i,c]*dis[i]^2 + b[c] )
//
// Block = 256 threads = 4 waves = 4 nodes, all on channel group g = blockIdx&7
// (channels [32g, 32g+32)). Round-robin dispatch pins group g to XCD g, so the
// per-XCD gather working set is 50k*32ch*fp16 = 3.2 MB < 4 MB L2 -> gathers go
// L2-resident (vs 25.6 MB whole-array working set = 188 MB refetch before).
// Wave lane layout: 8 edge slots x 8 lanes; lane loads 8 B (4 ch) -> one
// coalesced 64 B transaction per gathered row. Dead edge slots get w=0/src=0
// (dummy loads hit L1-hot row 0) -> no tail code. Cross-slot reduction:
// 3 shfl_xor rounds. csr loaded non-temporally so the edge stream does not
// evict the xh slice from L2.
// ---------------------------------------------------------------------------
__global__ __launch_bounds__(256) void k_agg(const __half* __restrict__ xh,
                                             const int* __restrict__ rowptr,
                                             const int* __restrict__ csr,
                                             const float* __restrict__ dis,
                                             const float* __restrict__ bias,
                                             __half* __restrict__ outh, int n) {
    int g = blockIdx.x & 7;                          // channel group == XCD (heuristic)
    int i = (blockIdx.x >> 3) * 4 + (threadIdx.x >> 6);
    if (i >= n) return;
    int lane = threadIdx.x & 63;
    int esub = lane >> 3;                            // edge slot within 8-wide bundle
    int cq   = lane & 7;                             // 8 lanes x 4 ch = 32 channels
    int cbase = g * 32 + cq * 4;
    const __half* xcol = xh + cbase;                 // lane's fixed column offset

    float disd = dis[i];
    int e0 = rowptr[i], e1 = rowptr[i + 1];

    float a0 = 0.0f, a1 = 0.0f, a2 = 0.0f, a3 = 0.0f;

    for (int e = e0; e < e1; e += 64) {
        int cnt = min(64, e1 - e);
        int sreg = 0; float wreg = 0.0f;
        if (lane < cnt) {
            sreg = __builtin_nontemporal_load(&csr[e + lane]);
            wreg = dis[sreg] * disd;
        }
        for (int j = 0; j < cnt; j += 8) {
            int   s = __shfl(sreg, j + esub);
            float w = __shfl(wreg, j + esub);
            uint2 v = *reinterpret_cast<const uint2*>(&xcol[(size_t)s * HID]);
            float2 f0 = __half22float2(*reinterpret_cast<__half2*>(&v.x));
            float2 f1 = __half22float2(*reinterpret_cast<__half2*>(&v.y));
            a0 = fmaf(f0.x, w, a0); a1 = fmaf(f0.y, w, a1);
            a2 = fmaf(f1.x, w, a2); a3 = fmaf(f1.y, w, a3);
        }
    }

    // reduce the 8 edge slots (lanes differing in bits 3..5)
    #pragma unroll
    for (int m = 8; m < 64; m <<= 1) {
        a0 += __shfl_xor(a0, m);
        a1 += __shfl_xor(a1, m);
        a2 += __shfl_xor(a2, m);
        a3 += __shfl_xor(a3, m);
    }

    if (esub == 0) {
        // self-loop term + bias + relu, write 8 B per lane (64 B per wave)
        uint2 v = *reinterpret_cast<const uint2*>(&xcol[(size_t)i * HID]);
        float2 f0 = __half22float2(*reinterpret_cast<__half2*>(&v.x));
        float2 f1 = __half22float2(*reinterpret_cast<__half2*>(&v.y));
        float ws = disd * disd;
        a0 = fmaf(f0.x, ws, a0); a1 = fmaf(f0.y, ws, a1);
        a2 = fmaf(f1.x, ws, a2); a3 = fmaf(f1.y, ws, a3);
        float4 bb = *reinterpret_cast<const float4*>(&bias[cbase]);
        union { __half2 h2[2]; uint2 u; } o;
        o.h2[0] = __floats2half2_rn(fmaxf(a0 + bb.x, 0.0f), fmaxf(a1 + bb.y, 0.0f));
        o.h2[1] = __floats2half2_rn(fmaxf(a2 + bb.z, 0.0f), fmaxf(a3 + bb.w, 0.0f));
        *reinterpret_cast<uint2*>(&outh[(size_t)i * HID + cbase]) = o.u;
    }
}

// ---------------------------------------------------------------------------
extern "C" void kernel_launch(void* const* d_in, const int* in_sizes, int n_in,
                              void* d_out, int out_size, void* d_ws, size_t ws_size,
                              hipStream_t stream) {
    const float* x     = (const float*)d_in[0];
    const float* rni   = (const float*)d_in[1];
    const unsigned int* ew = (const unsigned int*)d_in[2];
    const float* W1    = (const float*)d_in[3];
    const float* b1    = (const float*)d_in[4];
    const float* W2    = (const float*)d_in[5];
    const float* b2    = (const float*)d_in[6];
    const float* W_out = (const float*)d_in[7];
    const float* b_out = (const float*)d_in[8];
    float* out = (float*)d_out;

    const int n  = in_sizes[0] / D_IN;     // 50000
    const int e  = in_sizes[2] / 2;        // 800000
    const int nb = (n + 1023) / 1024;
    const int K1 = D_IN + D_RNI;           // 160

    char* ws = (char*)d_ws;
    size_t off = 0;
    auto carve = [&](size_t bytes) {
        char* p = ws + off;
        off = (off + bytes + 255) & ~(size_t)255;
        return p;
    };
    __half* xh    = (__half*)carve((size_t)n * HID * sizeof(__half));   // 25.6 MB
    __half* h     = (__half*)carve((size_t)n * HID * sizeof(__half));   // 25.6 MB
    __half* W1t   = (__half*)carve((size_t)K1 * HID * sizeof(__half));
    __half* W2t   = (__half*)carve((size_t)HID * HID * sizeof(__half));
    __half* Wot   = (__half*)carve((size_t)HID * HID * sizeof(__half));
    int*   counts = (int*)carve((size_t)n * sizeof(int));
    int*   incl   = (int*)carve((size_t)n * sizeof(int));
    int*   bsum   = (int*)carve((size_t)(nb + 1) * sizeof(int));
    int*   rowptr = (int*)carve((size_t)(n + 1) * sizeof(int));
    int*   cursor = (int*)carve((size_t)n * sizeof(int));
    float* dis    = (float*)carve((size_t)n * sizeof(float));
    int*   csr    = (int*)carve((size_t)e * sizeof(int));
    int*   mode   = (int*)carve(sizeof(int));
    (void)ws_size;

    const int eb = (e + 255) / 256;
    const int gemm_blocks = (n + 63) / 64;
    const int agg_blocks  = ((n + 3) / 4) * 8;   // x8 channel groups

    // --- CSR build
    k_detect<<<1, 256, 0, stream>>>(ew, 2 * e, mode);
    hipMemsetAsync(counts, 0, (size_t)n * sizeof(int), stream);
    k_count<<<eb, 256, 0, stream>>>(ew, mode, counts, e);
    k_scan1<<<nb, 1024, 0, stream>>>(counts, incl, bsum, n);
    k_scan2<<<1, 1024, 0, stream>>>(bsum, nb);
    k_scan3<<<(n + 255) / 256, 256, 0, stream>>>(counts, incl, bsum, rowptr, cursor, dis, n, nb);
    k_scatter<<<eb, 256, 0, stream>>>(ew, mode, cursor, csr, e);

    // --- weight transposes (tiny)
    {
        int tw1 = K1 * HID;
        k_cvt_wt<<<(tw1 + 255) / 256, 256, 0, stream>>>(W1, W1t, K1, HID, tw1);
        int tw = HID * HID;
        k_cvt_wt<<<(tw + 255) / 256, 256, 0, stream>>>(W2, W2t, HID, HID, tw);
        k_cvt_wt<<<(tw + 255) / 256, 256, 0, stream>>>(W_out, Wot, HID, HID, tw);
    }

    // --- layer 1 (fp32 inputs converted in GEMM staging)
    k_mgemm<true, false, true><<<gemm_blocks, 256, 0, stream>>>(x, D_IN, D_IN, rni, D_RNI,
                                                                W1t, nullptr, xh, n, K1);
    k_agg<<<agg_blocks, 256, 0, stream>>>(xh, rowptr, csr, dis, b1, h, n);

    // --- layer 2
    k_mgemm<false, false, true><<<gemm_blocks, 256, 0, stream>>>(h, HID, HID, nullptr, 0,
                                                                 W2t, nullptr, xh, n, HID);
    k_agg<<<agg_blocks, 256, 0, stream>>>(xh, rowptr, csr, dis, b2, h, n);

    // --- output layer (fp32 out + bias)
    k_mgemm<false, true, false><<<gemm_blocks, 256, 0, stream>>>(h, HID, HID, nullptr, 0,
                                                                 Wot, b_out, out, n, HID);
}

// Round 2
// 399.183 us; speedup vs baseline: 1.5214x; 1.5214x over previous
//
#include <hip/hip_runtime.h>
#include <hip/hip_bf16.h>
#include <hip/hip_fp16.h>
#include <math.h>

#define D_IN   128
#define D_RNI  32
#define HID    256

typedef _Float16 half8 __attribute__((ext_vector_type(8)));
typedef float    f32x4 __attribute__((ext_vector_type(4)));

// ---------------------------------------------------------------------------
// Edge dtype detection: int64 edges (values < 2^31) have all odd words zero.
// ---------------------------------------------------------------------------
__global__ void k_detect(const unsigned int* __restrict__ w, int nwords, int* __restrict__ mode) {
    __shared__ unsigned int red[256];
    unsigned int acc = 0;
    for (int i = threadIdx.x; i < 1024; i += 256) {
        int idx = 2 * i + 1;
        if (idx < nwords) acc |= w[idx];
    }
    red[threadIdx.x] = acc;
    __syncthreads();
    for (int s = 128; s > 0; s >>= 1) {
        if (threadIdx.x < s) red[threadIdx.x] |= red[threadIdx.x + s];
        __syncthreads();
    }
    if (threadIdx.x == 0) *mode = (red[0] == 0u) ? 1 : 0;
}

__global__ void k_count(const unsigned int* __restrict__ ew, const int* __restrict__ mode_p,
                        int* __restrict__ counts, int e) {
    int mode = *mode_p;
    int i = blockIdx.x * 256 + threadIdx.x;
    if (i >= e) return;
    int d = mode ? (int)ew[2 * ((size_t)e + i)] : (int)ew[(size_t)e + i];
    atomicAdd(&counts[d], 1);
}

// ---------------------------------------------------------------------------
// Hierarchical scan
// ---------------------------------------------------------------------------
__global__ __launch_bounds__(1024) void k_scan1(const int* __restrict__ counts,
                                                int* __restrict__ incl,
                                                int* __restrict__ bsum, int n) {
    __shared__ int sd[1024];
    int t = threadIdx.x;
    int i = blockIdx.x * 1024 + t;
    int v = (i < n) ? counts[i] : 0;
    sd[t] = v;
    __syncthreads();
    for (int off = 1; off < 1024; off <<= 1) {
        int tmp = (t >= off) ? sd[t - off] : 0;
        __syncthreads();
        sd[t] += tmp;
        __syncthreads();
    }
    if (i < n) incl[i] = sd[t];
    if (t == 1023) bsum[blockIdx.x] = sd[1023];
}

__global__ __launch_bounds__(1024) void k_scan2(int* __restrict__ bsum, int nb) {
    __shared__ int sd[1024];
    int t = threadIdx.x;
    int v = (t < nb) ? bsum[t] : 0;
    sd[t] = v;
    __syncthreads();
    for (int off = 1; off < 1024; off <<= 1) {
        int tmp = (t >= off) ? sd[t - off] : 0;
        __syncthreads();
        sd[t] += tmp;
        __syncthreads();
    }
    if (t < nb) bsum[t] = sd[t] - v;
    if (t == nb - 1) bsum[nb] = sd[t];
}

__global__ void k_scan3(const int* __restrict__ counts, const int* __restrict__ incl,
                        const int* __restrict__ bsum,
                        int* __restrict__ rowptr, int* __restrict__ cursor,
                        float* __restrict__ dis, int n, int nb) {
    int i = blockIdx.x * 256 + threadIdx.x;
    if (i >= n) return;
    int excl = incl[i] - counts[i] + bsum[i >> 10];
    rowptr[i] = excl;
    cursor[i] = excl;
    dis[i] = 1.0f / sqrtf((float)(counts[i] + 1));
    if (i == 0) rowptr[n] = bsum[nb];
}

__global__ void k_scatter(const unsigned int* __restrict__ ew, const int* __restrict__ mode_p,
                          int* __restrict__ cursor, int* __restrict__ csr, int e) {
    int mode = *mode_p;
    int i = blockIdx.x * 256 + threadIdx.x;
    if (i >= e) return;
    int s, d;
    if (mode) {
        s = (int)ew[2 * (size_t)i];
        d = (int)ew[2 * ((size_t)e + i)];
    } else {
        s = (int)ew[(size_t)i];
        d = (int)ew[(size_t)e + i];
    }
    int pos = atomicAdd(&cursor[d], 1);
    csr[pos] = s;
}

// W[K][N] fp32 -> Wt[N][K] fp16 (transpose + cast; tiny matrices)
__global__ void k_cvt_wt(const float* __restrict__ W, __half* __restrict__ Wt,
                         int K, int N, int total) {
    int i = blockIdx.x * 256 + threadIdx.x;
    if (i >= total) return;
    int k = i / N, nn = i - k * N;
    Wt[(size_t)nn * K + k] = __float2half(W[i]);
}

// ---------------------------------------------------------------------------
// fp16 MFMA GEMM: C[M x 256] = A[M x K] @ Bt^T  (Bt:[N=256][K] fp16).
// A_F32: A (and optional A2, concat along K at KA) are fp32, converted to fp16
// during LDS staging (fuses the input cast; K-split KA must be KT-aligned).
// Block: 256 threads = 4 waves; tile 64 M x 256 N; wave w owns N [64w, 64w+64).
// v_mfma_f32_16x16x32_f16; LDS rows padded to 40 halves (no 4-way+ conflicts).
// ---------------------------------------------------------------------------
#define KT 32
#define LSTR 40
template <bool A_F32, bool ADD_BIAS, bool HALF_OUT>
__global__ __launch_bounds__(256) void k_mgemm(const void* __restrict__ Av, int strideA, int KA,
                                               const void* __restrict__ A2v, int strideA2,
                                               const __half* __restrict__ Bt,
                                               const float* __restrict__ bias,
                                               void* Cv, int M, int K) {
    __shared__ __half As[64 * LSTR];
    __shared__ __half Bs[256 * LSTR];
    int tid = threadIdx.x;
    int wave = tid >> 6, lane = tid & 63;
    int q = lane >> 4, m16 = lane & 15;
    int r0 = blockIdx.x * 64;

    f32x4 acc[4][4] = {};

    for (int k0 = 0; k0 < K; k0 += KT) {
        __syncthreads();
        // stage A tile: 64 rows x 32 k (8 halves per thread)
        {
            int r = tid >> 2, kq = (tid & 3) * 8;
            int row = r0 + r; if (row >= M) row = M - 1;
            if (A_F32) {
                const float* src; int stride, kk0;
                if (k0 < KA) { src = (const float*)Av;  stride = strideA;  kk0 = k0; }
                else         { src = (const float*)A2v; stride = strideA2; kk0 = k0 - KA; }
                const float* p = &src[(size_t)row * stride + kk0 + kq];
                float4 va = *reinterpret_cast<const float4*>(p);
                float4 vb = *reinterpret_cast<const float4*>(p + 4);
                union { __half2 h2[4]; uint4 u; } uu;
                uu.h2[0] = __floats2half2_rn(va.x, va.y);
                uu.h2[1] = __floats2half2_rn(va.z, va.w);
                uu.h2[2] = __floats2half2_rn(vb.x, vb.y);
                uu.h2[3] = __floats2half2_rn(vb.z, vb.w);
                *reinterpret_cast<uint4*>(&As[r * LSTR + kq]) = uu.u;
            } else {
                const __half* src = (const __half*)Av;
                uint4 v = *reinterpret_cast<const uint4*>(&src[(size_t)row * strideA + k0 + kq]);
                *reinterpret_cast<uint4*>(&As[r * LSTR + kq]) = v;
            }
        }
        // stage B tile: 256 n x 32 k
        {
            int nb = tid >> 2, kq = (tid & 3) * 8;
            #pragma unroll
            for (int i = 0; i < 4; ++i) {
                int nn = nb + i * 64;
                uint4 v = *reinterpret_cast<const uint4*>(&Bt[(size_t)nn * K + k0 + kq]);
                *reinterpret_cast<uint4*>(&Bs[nn * LSTR + kq]) = v;
            }
        }
        __syncthreads();

        half8 af[4], bf[4];
        #pragma unroll
        for (int mi = 0; mi < 4; ++mi)
            af[mi] = *reinterpret_cast<const half8*>(&As[(mi * 16 + m16) * LSTR + q * 8]);
        #pragma unroll
        for (int ni = 0; ni < 4; ++ni)
            bf[ni] = *reinterpret_cast<const half8*>(&Bs[(wave * 64 + ni * 16 + m16) * LSTR + q * 8]);
        #pragma unroll
        for (int mi = 0; mi < 4; ++mi)
            #pragma unroll
            for (int ni = 0; ni < 4; ++ni)
                acc[mi][ni] = __builtin_amdgcn_mfma_f32_16x16x32_f16(af[mi], bf[ni], acc[mi][ni], 0, 0, 0);
    }

    // epilogue
    #pragma unroll
    for (int mi = 0; mi < 4; ++mi) {
        #pragma unroll
        for (int r = 0; r < 4; ++r) {
            int row = r0 + mi * 16 + q * 4 + r;
            if (row >= M) continue;
            #pragma unroll
            for (int ni = 0; ni < 4; ++ni) {
                int col = wave * 64 + ni * 16 + m16;
                float v = acc[mi][ni][r];
                if (ADD_BIAS) v += bias[col];
                if (HALF_OUT) ((__half*)Cv)[(size_t)row * HID + col] = __float2half(v);
                else          ((float*)Cv)[(size_t)row * HID + col] = v;
            }
        }
    }
}

// ---------------------------------------------------------------------------
// Aggregation, wave-per-node, MLP-deep:
// h[i,c] = relu( sum_e xh[src_e,c]*dis[src]*dis[i] + xh[i,c]*dis[i]^2 + b[c] )
//
// 256-thread block = 4 waves = 4 nodes. Lane owns 4 channels (one 8B load per
// edge; the wave's 64 lanes cover the full 512 B row -> 4 cache lines,
// fully coalesced). Edge idx/weight staged in registers, broadcast via __shfl.
// Inner loop processes 8 edges per batch: 8 shuffles, then 8 INDEPENDENT uint2
// loads issued back-to-back (4 KB in flight per wave), then the FMA block.
// Round-1 post-mortem: VGPR_Count=24 showed the old 4-deep unroll was
// register-starved into ~1-2 loads in flight -> latency-bound at 46% HBM.
// Tail batches are zero-weight padded (dummy lanes read row 0, L1-hot), so
// there is no serial tail. csr is read non-temporally (pure stream; keep L2
// for the xh gather working set).
// ---------------------------------------------------------------------------
__global__ __launch_bounds__(256, 8) void k_agg(const __half* __restrict__ xh,
                                                const int* __restrict__ rowptr,
                                                const int* __restrict__ csr,
                                                const float* __restrict__ dis,
                                                const float* __restrict__ bias,
                                                __half* __restrict__ outh, int n) {
    int i = blockIdx.x * 4 + (threadIdx.x >> 6);
    if (i >= n) return;
    int lane = threadIdx.x & 63;
    int c4 = lane * 4;
    const __half* xcol = xh + c4;
    float disd = dis[i];
    int e0 = rowptr[i], e1 = rowptr[i + 1];

    float acc0, acc1, acc2, acc3;
    {
        uint2 v = *reinterpret_cast<const uint2*>(&xcol[(size_t)i * HID]);
        float2 f0 = __half22float2(*reinterpret_cast<__half2*>(&v.x));
        float2 f1 = __half22float2(*reinterpret_cast<__half2*>(&v.y));
        float ws = disd * disd;
        acc0 = f0.x * ws; acc1 = f0.y * ws; acc2 = f1.x * ws; acc3 = f1.y * ws;
    }

    for (int e = e0; e < e1; e += 64) {
        int cnt = min(64, e1 - e);
        int sreg = 0; float wreg = 0.0f;
        if (lane < cnt) {
            sreg = __builtin_nontemporal_load(&csr[e + lane]);
            wreg = dis[sreg] * disd;
        }
        int nbat = (cnt + 7) >> 3;   // full 8-batches; dummies have w=0, s=0
        for (int b = 0; b < nbat; ++b) {
            int j = b * 8;
            int   s0 = __shfl(sreg, j + 0), s1 = __shfl(sreg, j + 1);
            int   s2 = __shfl(sreg, j + 2), s3 = __shfl(sreg, j + 3);
            int   s4 = __shfl(sreg, j + 4), s5 = __shfl(sreg, j + 5);
            int   s6 = __shfl(sreg, j + 6), s7 = __shfl(sreg, j + 7);
            float w0 = __shfl(wreg, j + 0), w1 = __shfl(wreg, j + 1);
            float w2 = __shfl(wreg, j + 2), w3 = __shfl(wreg, j + 3);
            float w4 = __shfl(wreg, j + 4), w5 = __shfl(wreg, j + 5);
            float w6 = __shfl(wreg, j + 6), w7 = __shfl(wreg, j + 7);
            uint2 v0 = *reinterpret_cast<const uint2*>(&xcol[(size_t)s0 * HID]);
            uint2 v1 = *reinterpret_cast<const uint2*>(&xcol[(size_t)s1 * HID]);
            uint2 v2 = *reinterpret_cast<const uint2*>(&xcol[(size_t)s2 * HID]);
            uint2 v3 = *reinterpret_cast<const uint2*>(&xcol[(size_t)s3 * HID]);
            uint2 v4 = *reinterpret_cast<const uint2*>(&xcol[(size_t)s4 * HID]);
            uint2 v5 = *reinterpret_cast<const uint2*>(&xcol[(size_t)s5 * HID]);
            uint2 v6 = *reinterpret_cast<const uint2*>(&xcol[(size_t)s6 * HID]);
            uint2 v7 = *reinterpret_cast<const uint2*>(&xcol[(size_t)s7 * HID]);
            float2 a0 = __half22float2(*reinterpret_cast<__half2*>(&v0.x));
            float2 b0 = __half22float2(*reinterpret_cast<__half2*>(&v0.y));
            float2 a1 = __half22float2(*reinterpret_cast<__half2*>(&v1.x));
            float2 b1 = __half22float2(*reinterpret_cast<__half2*>(&v1.y));
            float2 a2 = __half22float2(*reinterpret_cast<__half2*>(&v2.x));
            float2 b2 = __half22float2(*reinterpret_cast<__half2*>(&v2.y));
            float2 a3 = __half22float2(*reinterpret_cast<__half2*>(&v3.x));
            float2 b3 = __half22float2(*reinterpret_cast<__half2*>(&v3.y));
            float2 a4 = __half22float2(*reinterpret_cast<__half2*>(&v4.x));
            float2 b4 = __half22float2(*reinterpret_cast<__half2*>(&v4.y));
            float2 a5 = __half22float2(*reinterpret_cast<__half2*>(&v5.x));
            float2 b5 = __half22float2(*reinterpret_cast<__half2*>(&v5.y));
            float2 a6 = __half22float2(*reinterpret_cast<__half2*>(&v6.x));
            float2 b6 = __half22float2(*reinterpret_cast<__half2*>(&v6.y));
            float2 a7 = __half22float2(*reinterpret_cast<__half2*>(&v7.x));
            float2 b7 = __half22float2(*reinterpret_cast<__half2*>(&v7.y));
            acc0 = fmaf(a0.x, w0, acc0); acc1 = fmaf(a0.y, w0, acc1);
            acc2 = fmaf(b0.x, w0, acc2); acc3 = fmaf(b0.y, w0, acc3);
            acc0 = fmaf(a1.x, w1, acc0); acc1 = fmaf(a1.y, w1, acc1);
            acc2 = fmaf(b1.x, w1, acc2); acc3 = fmaf(b1.y, w1, acc3);
            acc0 = fmaf(a2.x, w2, acc0); acc1 = fmaf(a2.y, w2, acc1);
            acc2 = fmaf(b2.x, w2, acc2); acc3 = fmaf(b2.y, w2, acc3);
            acc0 = fmaf(a3.x, w3, acc0); acc1 = fmaf(a3.y, w3, acc1);
            acc2 = fmaf(b3.x, w3, acc2); acc3 = fmaf(b3.y, w3, acc3);
            acc0 = fmaf(a4.x, w4, acc0); acc1 = fmaf(a4.y, w4, acc1);
            acc2 = fmaf(b4.x, w4, acc2); acc3 = fmaf(b4.y, w4, acc3);
            acc0 = fmaf(a5.x, w5, acc0); acc1 = fmaf(a5.y, w5, acc1);
            acc2 = fmaf(b5.x, w5, acc2); acc3 = fmaf(b5.y, w5, acc3);
            acc0 = fmaf(a6.x, w6, acc0); acc1 = fmaf(a6.y, w6, acc1);
            acc2 = fmaf(b6.x, w6, acc2); acc3 = fmaf(b6.y, w6, acc3);
            acc0 = fmaf(a7.x, w7, acc0); acc1 = fmaf(a7.y, w7, acc1);
            acc2 = fmaf(b7.x, w7, acc2); acc3 = fmaf(b7.y, w7, acc3);
        }
    }

    float4 bb = *reinterpret_cast<const float4*>(&bias[c4]);
    union { __half2 h2[2]; uint2 u; } o;
    o.h2[0] = __floats2half2_rn(fmaxf(acc0 + bb.x, 0.0f), fmaxf(acc1 + bb.y, 0.0f));
    o.h2[1] = __floats2half2_rn(fmaxf(acc2 + bb.z, 0.0f), fmaxf(acc3 + bb.w, 0.0f));
    *reinterpret_cast<uint2*>(&outh[(size_t)i * HID + c4]) = o.u;
}

// ---------------------------------------------------------------------------
extern "C" void kernel_launch(void* const* d_in, const int* in_sizes, int n_in,
                              void* d_out, int out_size, void* d_ws, size_t ws_size,
                              hipStream_t stream) {
    const float* x     = (const float*)d_in[0];
    const float* rni   = (const float*)d_in[1];
    const unsigned int* ew = (const unsigned int*)d_in[2];
    const float* W1    = (const float*)d_in[3];
    const float* b1    = (const float*)d_in[4];
    const float* W2    = (const float*)d_in[5];
    const float* b2    = (const float*)d_in[6];
    const float* W_out = (const float*)d_in[7];
    const float* b_out = (const float*)d_in[8];
    float* out = (float*)d_out;

    const int n  = in_sizes[0] / D_IN;     // 50000
    const int e  = in_sizes[2] / 2;        // 800000
    const int nb = (n + 1023) / 1024;
    const int K1 = D_IN + D_RNI;           // 160

    char* ws = (char*)d_ws;
    size_t off = 0;
    auto carve = [&](size_t bytes) {
        char* p = ws + off;
        off = (off + bytes + 255) & ~(size_t)255;
        return p;
    };
    __half* xh    = (__half*)carve((size_t)n * HID * sizeof(__half));   // 25.6 MB
    __half* h     = (__half*)carve((size_t)n * HID * sizeof(__half));   // 25.6 MB
    __half* W1t   = (__half*)carve((size_t)K1 * HID * sizeof(__half));
    __half* W2t   = (__half*)carve((size_t)HID * HID * sizeof(__half));
    __half* Wot   = (__half*)carve((size_t)HID * HID * sizeof(__half));
    int*   counts = (int*)carve((size_t)n * sizeof(int));
    int*   incl   = (int*)carve((size_t)n * sizeof(int));
    int*   bsum   = (int*)carve((size_t)(nb + 1) * sizeof(int));
    int*   rowptr = (int*)carve((size_t)(n + 1) * sizeof(int));
    int*   cursor = (int*)carve((size_t)n * sizeof(int));
    float* dis    = (float*)carve((size_t)n * sizeof(float));
    int*   csr    = (int*)carve((size_t)e * sizeof(int));
    int*   mode   = (int*)carve(sizeof(int));
    (void)ws_size;

    const int eb = (e + 255) / 256;
    const int gemm_blocks = (n + 63) / 64;
    const int agg_blocks  = (n + 3) / 4;

    // --- CSR build
    k_detect<<<1, 256, 0, stream>>>(ew, 2 * e, mode);
    hipMemsetAsync(counts, 0, (size_t)n * sizeof(int), stream);
    k_count<<<eb, 256, 0, stream>>>(ew, mode, counts, e);
    k_scan1<<<nb, 1024, 0, stream>>>(counts, incl, bsum, n);
    k_scan2<<<1, 1024, 0, stream>>>(bsum, nb);
    k_scan3<<<(n + 255) / 256, 256, 0, stream>>>(counts, incl, bsum, rowptr, cursor, dis, n, nb);
    k_scatter<<<eb, 256, 0, stream>>>(ew, mode, cursor, csr, e);

    // --- weight transposes (tiny)
    {
        int tw1 = K1 * HID;
        k_cvt_wt<<<(tw1 + 255) / 256, 256, 0, stream>>>(W1, W1t, K1, HID, tw1);
        int tw = HID * HID;
        k_cvt_wt<<<(tw + 255) / 256, 256, 0, stream>>>(W2, W2t, HID, HID, tw);
        k_cvt_wt<<<(tw + 255) / 256, 256, 0, stream>>>(W_out, Wot, HID, HID, tw);
    }

    // --- layer 1 (fp32 inputs converted in GEMM staging)
    k_mgemm<true, false, true><<<gemm_blocks, 256, 0, stream>>>(x, D_IN, D_IN, rni, D_RNI,
                                                                W1t, nullptr, xh, n, K1);
    k_agg<<<agg_blocks, 256, 0, stream>>>(xh, rowptr, csr, dis, b1, h, n);

    // --- layer 2
    k_mgemm<false, false, true><<<gemm_blocks, 256, 0, stream>>>(h, HID, HID, nullptr, 0,
                                                                 W2t, nullptr, xh, n, HID);
    k_agg<<<agg_blocks, 256, 0, stream>>>(xh, rowptr, csr, dis, b2, h, n);

    // --- output layer (fp32 out + bias)
    k_mgemm<false, true, false><<<gemm_blocks, 256, 0, stream>>>(h, HID, HID, nullptr, 0,
                                                                 Wot, b_out, out, n, HID);
}

// Round 3
// 368.302 us; speedup vs baseline: 1.6490x; 1.0838x over previous
//
#include <hip/hip_runtime.h>
#include <hip/hip_bf16.h>
#include <hip/hip_fp16.h>
#include <math.h>

#define D_IN   128
#define D_RNI  32
#define HID    256

typedef _Float16 half8 __attribute__((ext_vector_type(8)));
typedef float    f32x4 __attribute__((ext_vector_type(4)));

// ---------------------------------------------------------------------------
// Edge dtype detection: int64 edges (values < 2^31) have all odd words zero.
// ---------------------------------------------------------------------------
__global__ void k_detect(const unsigned int* __restrict__ w, int nwords, int* __restrict__ mode) {
    __shared__ unsigned int red[256];
    unsigned int acc = 0;
    for (int i = threadIdx.x; i < 1024; i += 256) {
        int idx = 2 * i + 1;
        if (idx < nwords) acc |= w[idx];
    }
    red[threadIdx.x] = acc;
    __syncthreads();
    for (int s = 128; s > 0; s >>= 1) {
        if (threadIdx.x < s) red[threadIdx.x] |= red[threadIdx.x + s];
        __syncthreads();
    }
    if (threadIdx.x == 0) *mode = (red[0] == 0u) ? 1 : 0;
}

__global__ void k_count(const unsigned int* __restrict__ ew, const int* __restrict__ mode_p,
                        int* __restrict__ counts, int e) {
    int mode = *mode_p;
    int i = blockIdx.x * 256 + threadIdx.x;
    if (i >= e) return;
    int d = mode ? (int)ew[2 * ((size_t)e + i)] : (int)ew[(size_t)e + i];
    atomicAdd(&counts[d], 1);
}

// ---------------------------------------------------------------------------
// Hierarchical scan
// ---------------------------------------------------------------------------
__global__ __launch_bounds__(1024) void k_scan1(const int* __restrict__ counts,
                                                int* __restrict__ incl,
                                                int* __restrict__ bsum, int n) {
    __shared__ int sd[1024];
    int t = threadIdx.x;
    int i = blockIdx.x * 1024 + t;
    int v = (i < n) ? counts[i] : 0;
    sd[t] = v;
    __syncthreads();
    for (int off = 1; off < 1024; off <<= 1) {
        int tmp = (t >= off) ? sd[t - off] : 0;
        __syncthreads();
        sd[t] += tmp;
        __syncthreads();
    }
    if (i < n) incl[i] = sd[t];
    if (t == 1023) bsum[blockIdx.x] = sd[1023];
}

__global__ __launch_bounds__(1024) void k_scan2(int* __restrict__ bsum, int nb) {
    __shared__ int sd[1024];
    int t = threadIdx.x;
    int v = (t < nb) ? bsum[t] : 0;
    sd[t] = v;
    __syncthreads();
    for (int off = 1; off < 1024; off <<= 1) {
        int tmp = (t >= off) ? sd[t - off] : 0;
        __syncthreads();
        sd[t] += tmp;
        __syncthreads();
    }
    if (t < nb) bsum[t] = sd[t] - v;
    if (t == nb - 1) bsum[nb] = sd[t];
}

__global__ void k_scan3(const int* __restrict__ counts, const int* __restrict__ incl,
                        const int* __restrict__ bsum,
                        int* __restrict__ rowptr, int* __restrict__ cursor,
                        float* __restrict__ dis, int n, int nb) {
    int i = blockIdx.x * 256 + threadIdx.x;
    if (i >= n) return;
    int excl = incl[i] - counts[i] + bsum[i >> 10];
    rowptr[i] = excl;
    cursor[i] = excl;
    dis[i] = 1.0f / sqrtf((float)(counts[i] + 1));
    if (i == 0) rowptr[n] = bsum[nb];
}

__global__ void k_scatter(const unsigned int* __restrict__ ew, const int* __restrict__ mode_p,
                          int* __restrict__ cursor, int* __restrict__ csr, int e) {
    int mode = *mode_p;
    int i = blockIdx.x * 256 + threadIdx.x;
    if (i >= e) return;
    int s, d;
    if (mode) {
        s = (int)ew[2 * (size_t)i];
        d = (int)ew[2 * ((size_t)e + i)];
    } else {
        s = (int)ew[(size_t)i];
        d = (int)ew[(size_t)e + i];
    }
    int pos = atomicAdd(&cursor[d], 1);
    csr[pos] = s;
}

// W[K][N] fp32 -> Wt[N][K] fp16 (transpose + cast; tiny matrices)
__global__ void k_cvt_wt(const float* __restrict__ W, __half* __restrict__ Wt,
                         int K, int N, int total) {
    int i = blockIdx.x * 256 + threadIdx.x;
    if (i >= total) return;
    int k = i / N, nn = i - k * N;
    Wt[(size_t)nn * K + k] = __float2half(W[i]);
}

// ---------------------------------------------------------------------------
// fp16 MFMA GEMM: C[M x 256] = A[M x K] @ Bt^T  (Bt:[N=256][K] fp16).
// A_F32: A (and optional A2, concat along K at KA) are fp32, converted to fp16
// during LDS staging (fuses the input cast; K-split KA must be KT-aligned).
//
// Round-3 rewrite: 512 threads = 8 waves as 2(M)x4(N); tile 128 M x 256 N.
// Register double-buffer: global loads for K-step t+1 are issued right after
// the second barrier of step t and consumed at step t+1's LDS-write, so
// HBM/L2 latency hides under the MFMA phase instead of stalling each barrier.
// Halves B L2 re-reads and per-element barrier count vs the 64-row version.
// LDS rows padded to 40 halves (LSTR) - same verified fragment layout as the
// 64-row kernel, offset by the wave's (wm,wn) quadrant.
// ---------------------------------------------------------------------------
#define KT 32
#define LSTR 40
template <bool A_F32, bool ADD_BIAS, bool HALF_OUT>
__global__ __launch_bounds__(512) void k_mgemm(const void* __restrict__ Av, int strideA, int KA,
                                               const void* __restrict__ A2v, int strideA2,
                                               const __half* __restrict__ Bt,
                                               const float* __restrict__ bias,
                                               void* Cv, int M, int K) {
    __shared__ __half As[128 * LSTR];
    __shared__ __half Bs[256 * LSTR];
    int tid = threadIdx.x;
    int wave = tid >> 6, lane = tid & 63;
    int wm = wave >> 2, wn = wave & 3;          // 2 x 4 wave grid
    int q = lane >> 4, m16 = lane & 15;
    int r0 = blockIdx.x * 128;

    // staging coordinates
    int ar  = tid >> 2, akq = (tid & 3) * 8;    // A: 128 rows x 32 k, 16 B/thread
    int br  = tid >> 1, bkq = (tid & 1) * 16;   // B: 256 rows x 32 k, 32 B/thread

    int arow = r0 + ar; if (arow >= M) arow = M - 1;

    f32x4 acc[4][4] = {};

    // prefetch registers (tile t+1)
    float4 afr0, afr1;      // A_F32 path
    uint4  areg;            // A fp16 path
    uint4  breg0, breg1;

    auto loadA = [&](int k0) {
        if (A_F32) {
            const float* src; int stride, kk0;
            if (k0 < KA) { src = (const float*)Av;  stride = strideA;  kk0 = k0; }
            else         { src = (const float*)A2v; stride = strideA2; kk0 = k0 - KA; }
            const float* p = &src[(size_t)arow * stride + kk0 + akq];
            afr0 = *reinterpret_cast<const float4*>(p);
            afr1 = *reinterpret_cast<const float4*>(p + 4);
        } else {
            const __half* src = (const __half*)Av;
            areg = *reinterpret_cast<const uint4*>(&src[(size_t)arow * strideA + k0 + akq]);
        }
    };
    auto loadB = [&](int k0) {
        const __half* p = &Bt[(size_t)br * K + k0 + bkq];
        breg0 = *reinterpret_cast<const uint4*>(p);
        breg1 = *reinterpret_cast<const uint4*>(p + 8);
    };
    auto writeLDS = [&]() {
        if (A_F32) {
            union { __half2 h2[4]; uint4 u; } uu;
            uu.h2[0] = __floats2half2_rn(afr0.x, afr0.y);
            uu.h2[1] = __floats2half2_rn(afr0.z, afr0.w);
            uu.h2[2] = __floats2half2_rn(afr1.x, afr1.y);
            uu.h2[3] = __floats2half2_rn(afr1.z, afr1.w);
            *reinterpret_cast<uint4*>(&As[ar * LSTR + akq]) = uu.u;
        } else {
            *reinterpret_cast<uint4*>(&As[ar * LSTR + akq]) = areg;
        }
        *reinterpret_cast<uint4*>(&Bs[br * LSTR + bkq])     = breg0;
        *reinterpret_cast<uint4*>(&Bs[br * LSTR + bkq + 8]) = breg1;
    };

    loadA(0); loadB(0);
    for (int k0 = 0; k0 < K; k0 += KT) {
        __syncthreads();            // previous tile's consumers done
        writeLDS();                 // (compiler inserts vmcnt wait on prefetch regs)
        __syncthreads();
        if (k0 + KT < K) { loadA(k0 + KT); loadB(k0 + KT); }   // issue early; hidden under MFMA

        half8 af[4], bf[4];
        #pragma unroll
        for (int mi = 0; mi < 4; ++mi)
            af[mi] = *reinterpret_cast<const half8*>(&As[(wm * 64 + mi * 16 + m16) * LSTR + q * 8]);
        #pragma unroll
        for (int ni = 0; ni < 4; ++ni)
            bf[ni] = *reinterpret_cast<const half8*>(&Bs[(wn * 64 + ni * 16 + m16) * LSTR + q * 8]);
        #pragma unroll
        for (int mi = 0; mi < 4; ++mi)
            #pragma unroll
            for (int ni = 0; ni < 4; ++ni)
                acc[mi][ni] = __builtin_amdgcn_mfma_f32_16x16x32_f16(af[mi], bf[ni], acc[mi][ni], 0, 0, 0);
    }

    // epilogue
    #pragma unroll
    for (int mi = 0; mi < 4; ++mi) {
        #pragma unroll
        for (int r = 0; r < 4; ++r) {
            int row = r0 + wm * 64 + mi * 16 + q * 4 + r;
            if (row >= M) continue;
            #pragma unroll
            for (int ni = 0; ni < 4; ++ni) {
                int col = wn * 64 + ni * 16 + m16;
                float v = acc[mi][ni][r];
                if (ADD_BIAS) v += bias[col];
                if (HALF_OUT) ((__half*)Cv)[(size_t)row * HID + col] = __float2half(v);
                else          ((float*)Cv)[(size_t)row * HID + col] = v;
            }
        }
    }
}

// ---------------------------------------------------------------------------
// Aggregation, wave-per-node, barrier-free (round-0 verified version):
// h[i,c] = relu( sum_e xh[src_e,c]*dis[src]*dis[i] + xh[i,c]*dis[i]^2 + b[c] )
// 256-thread block = 4 waves = 4 nodes. Lane owns 4 channels (one 8B load per
// edge). Edge idx/weight staged in registers, broadcast via __shfl. 4-edge
// unroll -> 4 independent 8B loads in flight per lane.
// NOTE (rounds 1-2 post-mortem): this runs at ~59 us = 218 MB of L2-miss
// traffic at ~3.7-4 TB/s, the effective ceiling for this random-line gather.
// NT hints (+15 MB fetch) and deeper unrolls (+write-back shift) only ADD
// bytes; dur tracks bytes/3.7TB/s in every variant. Do not touch.
// ---------------------------------------------------------------------------
__global__ __launch_bounds__(256) void k_agg(const __half* __restrict__ xh,
                                             const int* __restrict__ rowptr,
                                             const int* __restrict__ csr,
                                             const float* __restrict__ dis,
                                             const float* __restrict__ bias,
                                             __half* __restrict__ outh, int n) {
    int i = blockIdx.x * 4 + (threadIdx.x >> 6);
    if (i >= n) return;
    int lane = threadIdx.x & 63;
    int c4 = lane * 4;
    float disd = dis[i];
    int e0 = rowptr[i], e1 = rowptr[i + 1];

    float acc0, acc1, acc2, acc3;
    {
        uint2 v = *reinterpret_cast<const uint2*>(&xh[(size_t)i * HID + c4]);
        float2 f0 = __half22float2(*reinterpret_cast<__half2*>(&v.x));
        float2 f1 = __half22float2(*reinterpret_cast<__half2*>(&v.y));
        float ws = disd * disd;
        acc0 = f0.x * ws; acc1 = f0.y * ws; acc2 = f1.x * ws; acc3 = f1.y * ws;
    }

    for (int e = e0; e < e1; e += 64) {
        int cnt = min(64, e1 - e);
        int sreg = 0; float wreg = 0.0f;
        if (lane < cnt) {
            sreg = csr[e + lane];
            wreg = dis[sreg] * disd;
        }
        int j = 0;
        for (; j + 4 <= cnt; j += 4) {
            int   s0 = __shfl(sreg, j + 0), s1 = __shfl(sreg, j + 1);
            int   s2 = __shfl(sreg, j + 2), s3 = __shfl(sreg, j + 3);
            float w0 = __shfl(wreg, j + 0), w1 = __shfl(wreg, j + 1);
            float w2 = __shfl(wreg, j + 2), w3 = __shfl(wreg, j + 3);
            uint2 v0 = *reinterpret_cast<const uint2*>(&xh[(size_t)s0 * HID + c4]);
            uint2 v1 = *reinterpret_cast<const uint2*>(&xh[(size_t)s1 * HID + c4]);
            uint2 v2 = *reinterpret_cast<const uint2*>(&xh[(size_t)s2 * HID + c4]);
            uint2 v3 = *reinterpret_cast<const uint2*>(&xh[(size_t)s3 * HID + c4]);
            float2 a0 = __half22float2(*reinterpret_cast<__half2*>(&v0.x));
            float2 b0 = __half22float2(*reinterpret_cast<__half2*>(&v0.y));
            float2 a1 = __half22float2(*reinterpret_cast<__half2*>(&v1.x));
            float2 b1 = __half22float2(*reinterpret_cast<__half2*>(&v1.y));
            float2 a2 = __half22float2(*reinterpret_cast<__half2*>(&v2.x));
            float2 b2 = __half22float2(*reinterpret_cast<__half2*>(&v2.y));
            float2 a3 = __half22float2(*reinterpret_cast<__half2*>(&v3.x));
            float2 b3 = __half22float2(*reinterpret_cast<__half2*>(&v3.y));
            acc0 = fmaf(a0.x, w0, acc0); acc1 = fmaf(a0.y, w0, acc1);
            acc2 = fmaf(b0.x, w0, acc2); acc3 = fmaf(b0.y, w0, acc3);
            acc0 = fmaf(a1.x, w1, acc0); acc1 = fmaf(a1.y, w1, acc1);
            acc2 = fmaf(b1.x, w1, acc2); acc3 = fmaf(b1.y, w1, acc3);
            acc0 = fmaf(a2.x, w2, acc0); acc1 = fmaf(a2.y, w2, acc1);
            acc2 = fmaf(b2.x, w2, acc2); acc3 = fmaf(b2.y, w2, acc3);
            acc0 = fmaf(a3.x, w3, acc0); acc1 = fmaf(a3.y, w3, acc1);
            acc2 = fmaf(b3.x, w3, acc2); acc3 = fmaf(b3.y, w3, acc3);
        }
        for (; j < cnt; ++j) {
            int   s = __shfl(sreg, j);
            float w = __shfl(wreg, j);
            uint2 v = *reinterpret_cast<const uint2*>(&xh[(size_t)s * HID + c4]);
            float2 a = __half22float2(*reinterpret_cast<__half2*>(&v.x));
            float2 b = __half22float2(*reinterpret_cast<__half2*>(&v.y));
            acc0 = fmaf(a.x, w, acc0); acc1 = fmaf(a.y, w, acc1);
            acc2 = fmaf(b.x, w, acc2); acc3 = fmaf(b.y, w, acc3);
        }
    }

    float4 bb = *reinterpret_cast<const float4*>(&bias[c4]);
    union { __half2 h2[2]; uint2 u; } o;
    o.h2[0] = __floats2half2_rn(fmaxf(acc0 + bb.x, 0.0f), fmaxf(acc1 + bb.y, 0.0f));
    o.h2[1] = __floats2half2_rn(fmaxf(acc2 + bb.z, 0.0f), fmaxf(acc3 + bb.w, 0.0f));
    *reinterpret_cast<uint2*>(&outh[(size_t)i * HID + c4]) = o.u;
}

// ---------------------------------------------------------------------------
extern "C" void kernel_launch(void* const* d_in, const int* in_sizes, int n_in,
                              void* d_out, int out_size, void* d_ws, size_t ws_size,
                              hipStream_t stream) {
    const float* x     = (const float*)d_in[0];
    const float* rni   = (const float*)d_in[1];
    const unsigned int* ew = (const unsigned int*)d_in[2];
    const float* W1    = (const float*)d_in[3];
    const float* b1    = (const float*)d_in[4];
    const float* W2    = (const float*)d_in[5];
    const float* b2    = (const float*)d_in[6];
    const float* W_out = (const float*)d_in[7];
    const float* b_out = (const float*)d_in[8];
    float* out = (float*)d_out;

    const int n  = in_sizes[0] / D_IN;     // 50000
    const int e  = in_sizes[2] / 2;        // 800000
    const int nb = (n + 1023) / 1024;
    const int K1 = D_IN + D_RNI;           // 160

    char* ws = (char*)d_ws;
    size_t off = 0;
    auto carve = [&](size_t bytes) {
        char* p = ws + off;
        off = (off + bytes + 255) & ~(size_t)255;
        return p;
    };
    __half* xh    = (__half*)carve((size_t)n * HID * sizeof(__half));   // 25.6 MB
    __half* h     = (__half*)carve((size_t)n * HID * sizeof(__half));   // 25.6 MB
    __half* W1t   = (__half*)carve((size_t)K1 * HID * sizeof(__half));
    __half* W2t   = (__half*)carve((size_t)HID * HID * sizeof(__half));
    __half* Wot   = (__half*)carve((size_t)HID * HID * sizeof(__half));
    int*   counts = (int*)carve((size_t)n * sizeof(int));
    int*   incl   = (int*)carve((size_t)n * sizeof(int));
    int*   bsum   = (int*)carve((size_t)(nb + 1) * sizeof(int));
    int*   rowptr = (int*)carve((size_t)(n + 1) * sizeof(int));
    int*   cursor = (int*)carve((size_t)n * sizeof(int));
    float* dis    = (float*)carve((size_t)n * sizeof(float));
    int*   csr    = (int*)carve((size_t)e * sizeof(int));
    int*   mode   = (int*)carve(sizeof(int));
    (void)ws_size;

    const int eb = (e + 255) / 256;
    const int gemm_blocks = (n + 127) / 128;
    const int agg_blocks  = (n + 3) / 4;

    // --- CSR build
    k_detect<<<1, 256, 0, stream>>>(ew, 2 * e, mode);
    hipMemsetAsync(counts, 0, (size_t)n * sizeof(int), stream);
    k_count<<<eb, 256, 0, stream>>>(ew, mode, counts, e);
    k_scan1<<<nb, 1024, 0, stream>>>(counts, incl, bsum, n);
    k_scan2<<<1, 1024, 0, stream>>>(bsum, nb);
    k_scan3<<<(n + 255) / 256, 256, 0, stream>>>(counts, incl, bsum, rowptr, cursor, dis, n, nb);
    k_scatter<<<eb, 256, 0, stream>>>(ew, mode, cursor, csr, e);

    // --- weight transposes (tiny)
    {
        int tw1 = K1 * HID;
        k_cvt_wt<<<(tw1 + 255) / 256, 256, 0, stream>>>(W1, W1t, K1, HID, tw1);
        int tw = HID * HID;
        k_cvt_wt<<<(tw + 255) / 256, 256, 0, stream>>>(W2, W2t, HID, HID, tw);
        k_cvt_wt<<<(tw + 255) / 256, 256, 0, stream>>>(W_out, Wot, HID, HID, tw);
    }

    // --- layer 1 (fp32 inputs converted in GEMM staging)
    k_mgemm<true, false, true><<<gemm_blocks, 512, 0, stream>>>(x, D_IN, D_IN, rni, D_RNI,
                                                                W1t, nullptr, xh, n, K1);
    k_agg<<<agg_blocks, 256, 0, stream>>>(xh, rowptr, csr, dis, b1, h, n);

    // --- layer 2
    k_mgemm<false, false, true><<<gemm_blocks, 512, 0, stream>>>(h, HID, HID, nullptr, 0,
                                                                 W2t, nullptr, xh, n, HID);
    k_agg<<<agg_blocks, 256, 0, stream>>>(xh, rowptr, csr, dis, b2, h, n);

    // --- output layer (fp32 out + bias)
    k_mgemm<false, true, false><<<gemm_blocks, 512, 0, stream>>>(h, HID, HID, nullptr, 0,
                                                                 Wot, b_out, out, n, HID);
}

// Round 4
// 361.366 us; speedup vs baseline: 1.6807x; 1.0192x over previous
//
#include <hip/hip_runtime.h>
#include <hip/hip_bf16.h>
#include <hip/hip_fp16.h>
#include <math.h>

#define D_IN   128
#define D_RNI  32
#define HID    256

typedef _Float16 half8 __attribute__((ext_vector_type(8)));
typedef float    f32x4 __attribute__((ext_vector_type(4)));

// ---------------------------------------------------------------------------
// k_prep: fused {edge dtype detect} + {3x weight transpose/cast}.
// Block 0: int64 edges (values < 2^31) have all odd words zero -> mode=1.
// Blocks 1..160:   W1 (160x256 fp32) -> W1t[256][160] fp16
// Blocks 161..416: W2 (256x256)      -> W2t[256][256]
// Blocks 417..672: W_out             -> Wot[256][256]
// ---------------------------------------------------------------------------
__global__ void k_prep(const unsigned int* __restrict__ ew, int nwords, int* __restrict__ mode,
                       const float* __restrict__ W1, __half* __restrict__ W1t,
                       const float* __restrict__ W2, __half* __restrict__ W2t,
                       const float* __restrict__ Wo, __half* __restrict__ Wot) {
    int b = blockIdx.x;
    if (b == 0) {
        __shared__ unsigned int red[256];
        unsigned int acc = 0;
        for (int i = threadIdx.x; i < 1024; i += 256) {
            int idx = 2 * i + 1;
            if (idx < nwords) acc |= ew[idx];
        }
        red[threadIdx.x] = acc;
        __syncthreads();
        for (int s = 128; s > 0; s >>= 1) {
            if (threadIdx.x < s) red[threadIdx.x] |= red[threadIdx.x + s];
            __syncthreads();
        }
        if (threadIdx.x == 0) *mode = (red[0] == 0u) ? 1 : 0;
        return;
    }
    int i = (b - 1) * 256 + threadIdx.x;
    const int T1 = (D_IN + D_RNI) * HID;   // 40960  (160 blocks)
    const int T2 = HID * HID;              // 65536  (256 blocks)
    if (i < T1) {
        int k = i / HID, nn = i - k * HID;
        W1t[(size_t)nn * (D_IN + D_RNI) + k] = __float2half(W1[i]);
    } else if (i < T1 + T2) {
        int j = i - T1;
        int k = j / HID, nn = j - k * HID;
        W2t[(size_t)nn * HID + k] = __float2half(W2[j]);
    } else {
        int j = i - T1 - T2;
        int k = j / HID, nn = j - k * HID;
        Wot[(size_t)nn * HID + k] = __float2half(Wo[j]);
    }
}

__global__ void k_count(const unsigned int* __restrict__ ew, const int* __restrict__ mode_p,
                        int* __restrict__ counts, int e) {
    int mode = *mode_p;
    int i = blockIdx.x * 256 + threadIdx.x;
    if (i >= e) return;
    int d = mode ? (int)ew[2 * ((size_t)e + i)] : (int)ew[(size_t)e + i];
    atomicAdd(&counts[d], 1);
}

// ---------------------------------------------------------------------------
// Scan: k_scan1 produces per-1024-chunk inclusive scans + raw chunk sums;
// k_scan3 folds the (<=64-entry) chunk-sum prefix in-kernel via a wave
// reduce (k_scan2 dispatch eliminated).
// ---------------------------------------------------------------------------
__global__ __launch_bounds__(1024) void k_scan1(const int* __restrict__ counts,
                                                int* __restrict__ incl,
                                                int* __restrict__ bsum, int n) {
    __shared__ int sd[1024];
    int t = threadIdx.x;
    int i = blockIdx.x * 1024 + t;
    int v = (i < n) ? counts[i] : 0;
    sd[t] = v;
    __syncthreads();
    for (int off = 1; off < 1024; off <<= 1) {
        int tmp = (t >= off) ? sd[t - off] : 0;
        __syncthreads();
        sd[t] += tmp;
        __syncthreads();
    }
    if (i < n) incl[i] = sd[t];
    if (t == 1023) bsum[blockIdx.x] = sd[1023];
}

__global__ void k_scan3(const int* __restrict__ counts, const int* __restrict__ incl,
                        const int* __restrict__ bsum,
                        int* __restrict__ rowptr, int* __restrict__ cursor,
                        float* __restrict__ dis, int n, int nb) {
    __shared__ int pre_s, tot_s;
    int t = threadIdx.x;
    int c = (blockIdx.x * 256) >> 10;           // this block's 1024-chunk index
    if (t < 64) {
        int v   = (t < nb) ? bsum[t] : 0;       // raw chunk sums
        int pre = (t < c)  ? v : 0;
        int tot = v;
        #pragma unroll
        for (int m = 32; m > 0; m >>= 1) {
            pre += __shfl_down(pre, m);
            tot += __shfl_down(tot, m);
        }
        if (t == 0) { pre_s = pre; tot_s = tot; }
    }
    __syncthreads();
    int i = blockIdx.x * 256 + t;
    if (i >= n) return;
    int excl = incl[i] - counts[i] + pre_s;
    rowptr[i] = excl;
    cursor[i] = excl;
    dis[i] = 1.0f / sqrtf((float)(counts[i] + 1));
    if (i == 0) rowptr[n] = tot_s;
}

__global__ void k_scatter(const unsigned int* __restrict__ ew, const int* __restrict__ mode_p,
                          int* __restrict__ cursor, int* __restrict__ csr, int e) {
    int mode = *mode_p;
    int i = blockIdx.x * 256 + threadIdx.x;
    if (i >= e) return;
    int s, d;
    if (mode) {
        s = (int)ew[2 * (size_t)i];
        d = (int)ew[2 * ((size_t)e + i)];
    } else {
        s = (int)ew[(size_t)i];
        d = (int)ew[(size_t)e + i];
    }
    int pos = atomicAdd(&cursor[d], 1);
    csr[pos] = s;
}

// ---------------------------------------------------------------------------
// fp16 MFMA GEMM: C[M x 256] = A[M x K] @ Bt^T  (Bt:[N=256][K] fp16).
// A_F32: A (and optional A2, concat along K at KA) are fp32, converted to fp16
// during LDS staging (fuses the input cast; K-split KA must be KT-aligned).
//
// 512 threads = 8 waves as 2(M)x4(N); tile 128 M x 256 N.
// Round-4: LDS double-buffer -> ONE barrier per K-step; global loads for step
// t+1 issued before step t's MFMAs, LDS-write after them (vmcnt wait hidden
// under MFMA). __launch_bounds__(512,4) caps VGPR at 128 so 2 blocks/CU stay
// resident (at ~140 VGPR only 1 block/CU fits -> poor latency hiding).
// LDS rows padded to 40 halves (LSTR) - verified fragment layout.
// ---------------------------------------------------------------------------
#define KT 32
#define LSTR 40
template <bool A_F32, bool ADD_BIAS, bool HALF_OUT>
__global__ __launch_bounds__(512, 4) void k_mgemm(const void* __restrict__ Av, int strideA, int KA,
                                                  const void* __restrict__ A2v, int strideA2,
                                                  const __half* __restrict__ Bt,
                                                  const float* __restrict__ bias,
                                                  void* Cv, int M, int K) {
    __shared__ __half As[2][128 * LSTR];
    __shared__ __half Bs[2][256 * LSTR];
    int tid = threadIdx.x;
    int wave = tid >> 6, lane = tid & 63;
    int wm = wave >> 2, wn = wave & 3;          // 2 x 4 wave grid
    int q = lane >> 4, m16 = lane & 15;
    int r0 = blockIdx.x * 128;

    // staging coordinates
    int ar  = tid >> 2, akq = (tid & 3) * 8;    // A: 128 rows x 32 k, 16 B/thread
    int br  = tid >> 1, bkq = (tid & 1) * 16;   // B: 256 rows x 32 k, 32 B/thread

    int arow = r0 + ar; if (arow >= M) arow = M - 1;

    f32x4 acc[4][4] = {};

    // prefetch registers (tile t+1)
    float4 afr0, afr1;      // A_F32 path
    uint4  areg;            // A fp16 path
    uint4  breg0, breg1;

    auto loadA = [&](int k0) {
        if (A_F32) {
            const float* src; int stride, kk0;
            if (k0 < KA) { src = (const float*)Av;  stride = strideA;  kk0 = k0; }
            else         { src = (const float*)A2v; stride = strideA2; kk0 = k0 - KA; }
            const float* p = &src[(size_t)arow * stride + kk0 + akq];
            afr0 = *reinterpret_cast<const float4*>(p);
            afr1 = *reinterpret_cast<const float4*>(p + 4);
        } else {
            const __half* src = (const __half*)Av;
            areg = *reinterpret_cast<const uint4*>(&src[(size_t)arow * strideA + k0 + akq]);
        }
    };
    auto loadB = [&](int k0) {
        const __half* p = &Bt[(size_t)br * K + k0 + bkq];
        breg0 = *reinterpret_cast<const uint4*>(p);
        breg1 = *reinterpret_cast<const uint4*>(p + 8);
    };
    auto writeLDS = [&](int buf) {
        if (A_F32) {
            union { __half2 h2[4]; uint4 u; } uu;
            uu.h2[0] = __floats2half2_rn(afr0.x, afr0.y);
            uu.h2[1] = __floats2half2_rn(afr0.z, afr0.w);
            uu.h2[2] = __floats2half2_rn(afr1.x, afr1.y);
            uu.h2[3] = __floats2half2_rn(afr1.z, afr1.w);
            *reinterpret_cast<uint4*>(&As[buf][ar * LSTR + akq]) = uu.u;
        } else {
            *reinterpret_cast<uint4*>(&As[buf][ar * LSTR + akq]) = areg;
        }
        *reinterpret_cast<uint4*>(&Bs[buf][br * LSTR + bkq])     = breg0;
        *reinterpret_cast<uint4*>(&Bs[buf][br * LSTR + bkq + 8]) = breg1;
    };

    const int S = K / KT;
    loadA(0); loadB(0);
    writeLDS(0);
    __syncthreads();

    for (int t = 0; t < S; ++t) {
        int cur = t & 1;
        if (t + 1 < S) { loadA((t + 1) * KT); loadB((t + 1) * KT); }  // hide under MFMA

        half8 af[4], bf[4];
        #pragma unroll
        for (int mi = 0; mi < 4; ++mi)
            af[mi] = *reinterpret_cast<const half8*>(&As[cur][(wm * 64 + mi * 16 + m16) * LSTR + q * 8]);
        #pragma unroll
        for (int ni = 0; ni < 4; ++ni)
            bf[ni] = *reinterpret_cast<const half8*>(&Bs[cur][(wn * 64 + ni * 16 + m16) * LSTR + q * 8]);
        #pragma unroll
        for (int mi = 0; mi < 4; ++mi)
            #pragma unroll
            for (int ni = 0; ni < 4; ++ni)
                acc[mi][ni] = __builtin_amdgcn_mfma_f32_16x16x32_f16(af[mi], bf[ni], acc[mi][ni], 0, 0, 0);

        if (t + 1 < S) writeLDS(cur ^ 1);   // waits vmcnt on prefetch regs, post-MFMA
        __syncthreads();                     // single barrier per K-step
    }

    // epilogue
    #pragma unroll
    for (int mi = 0; mi < 4; ++mi) {
        #pragma unroll
        for (int r = 0; r < 4; ++r) {
            int row = r0 + wm * 64 + mi * 16 + q * 4 + r;
            if (row >= M) continue;
            #pragma unroll
            for (int ni = 0; ni < 4; ++ni) {
                int col = wn * 64 + ni * 16 + m16;
                float v = acc[mi][ni][r];
                if (ADD_BIAS) v += bias[col];
                if (HALF_OUT) ((__half*)Cv)[(size_t)row * HID + col] = __float2half(v);
                else          ((float*)Cv)[(size_t)row * HID + col] = v;
            }
        }
    }
}

// ---------------------------------------------------------------------------
// Aggregation, wave-per-node, barrier-free (round-0 verified version):
// h[i,c] = relu( sum_e xh[src_e,c]*dis[src]*dis[i] + xh[i,c]*dis[i]^2 + b[c] )
// 256-thread block = 4 waves = 4 nodes. Lane owns 4 channels (one 8B load per
// edge). Edge idx/weight staged in registers, broadcast via __shfl. 4-edge
// unroll -> 4 independent 8B loads in flight per lane.
// NOTE (rounds 1-2 post-mortem): this runs at ~59 us = 218 MB of L2-miss
// traffic at ~3.7-4 TB/s, the effective ceiling for this random-line gather.
// NT hints (+15 MB fetch) and deeper unrolls (+write-back shift) only ADD
// bytes; dur tracks bytes/3.7TB/s in every variant. Do not touch.
// ---------------------------------------------------------------------------
__global__ __launch_bounds__(256) void k_agg(const __half* __restrict__ xh,
                                             const int* __restrict__ rowptr,
                                             const int* __restrict__ csr,
                                             const float* __restrict__ dis,
                                             const float* __restrict__ bias,
                                             __half* __restrict__ outh, int n) {
    int i = blockIdx.x * 4 + (threadIdx.x >> 6);
    if (i >= n) return;
    int lane = threadIdx.x & 63;
    int c4 = lane * 4;
    float disd = dis[i];
    int e0 = rowptr[i], e1 = rowptr[i + 1];

    float acc0, acc1, acc2, acc3;
    {
        uint2 v = *reinterpret_cast<const uint2*>(&xh[(size_t)i * HID + c4]);
        float2 f0 = __half22float2(*reinterpret_cast<__half2*>(&v.x));
        float2 f1 = __half22float2(*reinterpret_cast<__half2*>(&v.y));
        float ws = disd * disd;
        acc0 = f0.x * ws; acc1 = f0.y * ws; acc2 = f1.x * ws; acc3 = f1.y * ws;
    }

    for (int e = e0; e < e1; e += 64) {
        int cnt = min(64, e1 - e);
        int sreg = 0; float wreg = 0.0f;
        if (lane < cnt) {
            sreg = csr[e + lane];
            wreg = dis[sreg] * disd;
        }
        int j = 0;
        for (; j + 4 <= cnt; j += 4) {
            int   s0 = __shfl(sreg, j + 0), s1 = __shfl(sreg, j + 1);
            int   s2 = __shfl(sreg, j + 2), s3 = __shfl(sreg, j + 3);
            float w0 = __shfl(wreg, j + 0), w1 = __shfl(wreg, j + 1);
            float w2 = __shfl(wreg, j + 2), w3 = __shfl(wreg, j + 3);
            uint2 v0 = *reinterpret_cast<const uint2*>(&xh[(size_t)s0 * HID + c4]);
            uint2 v1 = *reinterpret_cast<const uint2*>(&xh[(size_t)s1 * HID + c4]);
            uint2 v2 = *reinterpret_cast<const uint2*>(&xh[(size_t)s2 * HID + c4]);
            uint2 v3 = *reinterpret_cast<const uint2*>(&xh[(size_t)s3 * HID + c4]);
            float2 a0 = __half22float2(*reinterpret_cast<__half2*>(&v0.x));
            float2 b0 = __half22float2(*reinterpret_cast<__half2*>(&v0.y));
            float2 a1 = __half22float2(*reinterpret_cast<__half2*>(&v1.x));
            float2 b1 = __half22float2(*reinterpret_cast<__half2*>(&v1.y));
            float2 a2 = __half22float2(*reinterpret_cast<__half2*>(&v2.x));
            float2 b2 = __half22float2(*reinterpret_cast<__half2*>(&v2.y));
            float2 a3 = __half22float2(*reinterpret_cast<__half2*>(&v3.x));
            float2 b3 = __half22float2(*reinterpret_cast<__half2*>(&v3.y));
            acc0 = fmaf(a0.x, w0, acc0); acc1 = fmaf(a0.y, w0, acc1);
            acc2 = fmaf(b0.x, w0, acc2); acc3 = fmaf(b0.y, w0, acc3);
            acc0 = fmaf(a1.x, w1, acc0); acc1 = fmaf(a1.y, w1, acc1);
            acc2 = fmaf(b1.x, w1, acc2); acc3 = fmaf(b1.y, w1, acc3);
            acc0 = fmaf(a2.x, w2, acc0); acc1 = fmaf(a2.y, w2, acc1);
            acc2 = fmaf(b2.x, w2, acc2); acc3 = fmaf(b2.y, w2, acc3);
            acc0 = fmaf(a3.x, w3, acc0); acc1 = fmaf(a3.y, w3, acc1);
            acc2 = fmaf(b3.x, w3, acc2); acc3 = fmaf(b3.y, w3, acc3);
        }
        for (; j < cnt; ++j) {
            int   s = __shfl(sreg, j);
            float w = __shfl(wreg, j);
            uint2 v = *reinterpret_cast<const uint2*>(&xh[(size_t)s * HID + c4]);
            float2 a = __half22float2(*reinterpret_cast<__half2*>(&v.x));
            float2 b = __half22float2(*reinterpret_cast<__half2*>(&v.y));
            acc0 = fmaf(a.x, w, acc0); acc1 = fmaf(a.y, w, acc1);
            acc2 = fmaf(b.x, w, acc2); acc3 = fmaf(b.y, w, acc3);
        }
    }

    float4 bb = *reinterpret_cast<const float4*>(&bias[c4]);
    union { __half2 h2[2]; uint2 u; } o;
    o.h2[0] = __floats2half2_rn(fmaxf(acc0 + bb.x, 0.0f), fmaxf(acc1 + bb.y, 0.0f));
    o.h2[1] = __floats2half2_rn(fmaxf(acc2 + bb.z, 0.0f), fmaxf(acc3 + bb.w, 0.0f));
    *reinterpret_cast<uint2*>(&outh[(size_t)i * HID + c4]) = o.u;
}

// ---------------------------------------------------------------------------
extern "C" void kernel_launch(void* const* d_in, const int* in_sizes, int n_in,
                              void* d_out, int out_size, void* d_ws, size_t ws_size,
                              hipStream_t stream) {
    const float* x     = (const float*)d_in[0];
    const float* rni   = (const float*)d_in[1];
    const unsigned int* ew = (const unsigned int*)d_in[2];
    const float* W1    = (const float*)d_in[3];
    const float* b1    = (const float*)d_in[4];
    const float* W2    = (const float*)d_in[5];
    const float* b2    = (const float*)d_in[6];
    const float* W_out = (const float*)d_in[7];
    const float* b_out = (const float*)d_in[8];
    float* out = (float*)d_out;

    const int n  = in_sizes[0] / D_IN;     // 50000
    const int e  = in_sizes[2] / 2;        // 800000
    const int nb = (n + 1023) / 1024;
    const int K1 = D_IN + D_RNI;           // 160

    char* ws = (char*)d_ws;
    size_t off = 0;
    auto carve = [&](size_t bytes) {
        char* p = ws + off;
        off = (off + bytes + 255) & ~(size_t)255;
        return p;
    };
    __half* xh    = (__half*)carve((size_t)n * HID * sizeof(__half));   // 25.6 MB
    __half* h     = (__half*)carve((size_t)n * HID * sizeof(__half));   // 25.6 MB
    __half* W1t   = (__half*)carve((size_t)K1 * HID * sizeof(__half));
    __half* W2t   = (__half*)carve((size_t)HID * HID * sizeof(__half));
    __half* Wot   = (__half*)carve((size_t)HID * HID * sizeof(__half));
    int*   counts = (int*)carve((size_t)n * sizeof(int));
    int*   incl   = (int*)carve((size_t)n * sizeof(int));
    int*   bsum   = (int*)carve((size_t)(nb + 1) * sizeof(int));
    int*   rowptr = (int*)carve((size_t)(n + 1) * sizeof(int));
    int*   cursor = (int*)carve((size_t)n * sizeof(int));
    float* dis    = (float*)carve((size_t)n * sizeof(float));
    int*   csr    = (int*)carve((size_t)e * sizeof(int));
    int*   mode   = (int*)carve(sizeof(int));
    (void)ws_size;

    const int eb = (e + 255) / 256;
    const int gemm_blocks = (n + 127) / 128;
    const int agg_blocks  = (n + 3) / 4;
    const int prep_blocks = 1 + (K1 * HID + 2 * HID * HID + 255) / 256;   // 673

    // --- prep (detect + weight cvt) and CSR build
    k_prep<<<prep_blocks, 256, 0, stream>>>(ew, 2 * e, mode, W1, W1t, W2, W2t, W_out, Wot);
    hipMemsetAsync(counts, 0, (size_t)n * sizeof(int), stream);
    k_count<<<eb, 256, 0, stream>>>(ew, mode, counts, e);
    k_scan1<<<nb, 1024, 0, stream>>>(counts, incl, bsum, n);
    k_scan3<<<(n + 255) / 256, 256, 0, stream>>>(counts, incl, bsum, rowptr, cursor, dis, n, nb);
    k_scatter<<<eb, 256, 0, stream>>>(ew, mode, cursor, csr, e);

    // --- layer 1 (fp32 inputs converted in GEMM staging)
    k_mgemm<true, false, true><<<gemm_blocks, 512, 0, stream>>>(x, D_IN, D_IN, rni, D_RNI,
                                                                W1t, nullptr, xh, n, K1);
    k_agg<<<agg_blocks, 256, 0, stream>>>(xh, rowptr, csr, dis, b1, h, n);

    // --- layer 2
    k_mgemm<false, false, true><<<gemm_blocks, 512, 0, stream>>>(h, HID, HID, nullptr, 0,
                                                                 W2t, nullptr, xh, n, HID);
    k_agg<<<agg_blocks, 256, 0, stream>>>(xh, rowptr, csr, dis, b2, h, n);

    // --- output layer (fp32 out + bias)
    k_mgemm<false, true, false><<<gemm_blocks, 512, 0, stream>>>(h, HID, HID, nullptr, 0,
                                                                 Wot, b_out, out, n, HID);
}